// Round 8
// baseline (4269.823 us; speedup 1.0000x reference)
//
#include <hip/hip_runtime.h>
#include <math.h>

// Problem constants (B=16, T=64, NN=4096, H=1024)
constexpr int kB = 16;
constexpr int kT = 64;
constexpr int kH = 1024;

typedef short bf16x8 __attribute__((ext_vector_type(8)));   // 8 bf16 = 4 VGPR
typedef float floatx4 __attribute__((ext_vector_type(4)));  // MFMA acc

// ---------------------------------------------------------------------------
// bf16 convert helpers
// ---------------------------------------------------------------------------
__device__ __forceinline__ unsigned short f2bf_rne(float f) {
    unsigned u = __float_as_uint(f);
    u = u + 0x7FFFu + ((u >> 16) & 1u);
    return (unsigned short)(u >> 16);
}
__device__ __forceinline__ unsigned f2bf_fast_u(float f) {
    return (__float_as_uint(f) + 0x8000u) >> 16;
}
__device__ __forceinline__ uint4 pack8(const float4 a, const float4 b) {
    uint4 r;
    r.x = f2bf_fast_u(a.x) | (f2bf_fast_u(a.y) << 16);
    r.y = f2bf_fast_u(a.z) | (f2bf_fast_u(a.w) << 16);
    r.z = f2bf_fast_u(b.x) | (f2bf_fast_u(b.y) << 16);
    r.w = f2bf_fast_u(b.z) | (f2bf_fast_u(b.w) << 16);
    return r;
}

__global__ __launch_bounds__(256)
void pack_bf16(const float* __restrict__ src, unsigned short* __restrict__ dst,
               int n4)
{
    const int i = blockIdx.x * 256 + threadIdx.x;
    if (i < n4) {
        const float4 v = ((const float4*)src)[i];
        ushort4 o;
        o.x = f2bf_rne(v.x); o.y = f2bf_rne(v.y);
        o.z = f2bf_rne(v.z); o.w = f2bf_rne(v.w);
        ((ushort4*)dst)[i] = o;
    }
}

// ---------------------------------------------------------------------------
// 64x64-tile fp32 GEMM (decoder only; M=16 guard): C = X@W^T + bias
// ---------------------------------------------------------------------------
#define GBM 64
#define GBN 64
#define GBK 16
#define GPAD 4

__global__ __launch_bounds__(256)
void gemm_nt_bias(const float* __restrict__ X, const float* __restrict__ W,
                  const float* __restrict__ bias, float* __restrict__ C,
                  int M, int N, int K)
{
    __shared__ float Xs[GBK][GBM + GPAD];
    __shared__ float Ws[GBK][GBN + GPAD];

    const int tid = threadIdx.x;
    const int bm = blockIdx.y * GBM;
    const int bn = blockIdx.x * GBN;
    const int tm = (tid >> 4) * 4;
    const int tn = (tid & 15) * 4;
    const int lr = tid >> 2;
    const int lc = (tid & 3) * 4;

    float acc[4][4] = {};

    for (int k0 = 0; k0 < K; k0 += GBK) {
        {
            const int gr = bm + lr;
            float4 v = make_float4(0.f, 0.f, 0.f, 0.f);
            if (gr < M) v = *(const float4*)(X + (long)gr * K + k0 + lc);
            Xs[lc + 0][lr] = v.x; Xs[lc + 1][lr] = v.y;
            Xs[lc + 2][lr] = v.z; Xs[lc + 3][lr] = v.w;
        }
        {
            const int gr = bn + lr;
            const float4 v = *(const float4*)(W + (long)gr * K + k0 + lc);
            Ws[lc + 0][lr] = v.x; Ws[lc + 1][lr] = v.y;
            Ws[lc + 2][lr] = v.z; Ws[lc + 3][lr] = v.w;
        }
        __syncthreads();
        #pragma unroll
        for (int k = 0; k < GBK; ++k) {
            const float4 a4 = *(const float4*)&Xs[k][tm];
            const float4 b4 = *(const float4*)&Ws[k][tn];
            acc[0][0] += a4.x * b4.x; acc[0][1] += a4.x * b4.y; acc[0][2] += a4.x * b4.z; acc[0][3] += a4.x * b4.w;
            acc[1][0] += a4.y * b4.x; acc[1][1] += a4.y * b4.y; acc[1][2] += a4.y * b4.z; acc[1][3] += a4.y * b4.w;
            acc[2][0] += a4.z * b4.x; acc[2][1] += a4.z * b4.y; acc[2][2] += a4.z * b4.z; acc[2][3] += a4.z * b4.w;
            acc[3][0] += a4.w * b4.x; acc[3][1] += a4.w * b4.y; acc[3][2] += a4.w * b4.z; acc[3][3] += a4.w * b4.w;
        }
        __syncthreads();
    }

    #pragma unroll
    for (int i = 0; i < 4; ++i) {
        const int gr = bm + tm + i;
        if (gr >= M) continue;
        #pragma unroll
        for (int jj = 0; jj < 4; ++jj) {
            const int gc = bn + tn + jj;
            C[(long)gr * N + gc] = acc[i][jj] + bias[gc];
        }
    }
}

// ---------------------------------------------------------------------------
// Phase-A MFMA GEMM with XOR-swizzled LDS (R7 had 9.4e6 bank conflicts from
// the 40-short pad: stride 20 dwords mod 32 collides 16-lane b128 phases).
// Now: row stride 32 shorts (16 dwords), physical k-chunk = c ^ ((row>>1)&3)
// -> 16-lane phases touch 8 distinct 4-bank groups x 2 = 2-way max (free).
// Tile 64(M)x128(N), BK=32, 4 waves; wave = 32x64 quadrant (2x4 MFMA tiles).
// ---------------------------------------------------------------------------
__device__ __forceinline__ int swz(int row, int c) {   // physical chunk
    return c ^ ((row >> 1) & 3);
}

__global__ __launch_bounds__(256)
void gemm_mfma_a(const float* __restrict__ X,   // [M,K]
                 const float* __restrict__ W,   // [N,K]
                 const float* __restrict__ bias,// [N]
                 float* __restrict__ C,         // [M,N]
                 int M, int N, int K)
{
    __shared__ __attribute__((aligned(16))) unsigned short As[64 * 32];
    __shared__ __attribute__((aligned(16))) unsigned short Bs[128 * 32];

    const int tid  = threadIdx.x;
    const int lane = tid & 63;
    const int w    = tid >> 6;
    const int qm   = w & 1;            // 32-row half
    const int qn   = w >> 1;           // 64-col half
    const int bm   = blockIdx.y * 64;
    const int bn   = blockIdx.x * 128;
    const int al   = lane & 15;
    const int aq   = lane >> 4;

    floatx4 acc[2][4];
    #pragma unroll
    for (int i = 0; i < 2; ++i)
        #pragma unroll
        for (int j = 0; j < 4; ++j)
            acc[i][j] = (floatx4){0.f, 0.f, 0.f, 0.f};

    const int ar = tid >> 2;           // A loader row 0..63
    const int ac = tid & 3;            // logical k-chunk 0..3

    for (int k0 = 0; k0 < K; k0 += 32) {
        const float* ap = X + (long)(bm + ar) * K + k0 + ac * 8;
        const float4 av0 = *(const float4*)(ap);
        const float4 av1 = *(const float4*)(ap + 4);
        float4 bv0[2], bv1[2];
        #pragma unroll
        for (int l = 0; l < 2; ++l) {
            const int c = tid + 256 * l;        // 0..511
            const float* bp = W + (long)(bn + (c >> 2)) * K + k0 + (c & 3) * 8;
            bv0[l] = *(const float4*)(bp);
            bv1[l] = *(const float4*)(bp + 4);
        }
        __syncthreads();   // previous tile's readers done
        *(uint4*)&As[ar * 32 + swz(ar, ac) * 8] = pack8(av0, av1);
        #pragma unroll
        for (int l = 0; l < 2; ++l) {
            const int c = tid + 256 * l;
            const int r = c >> 2;
            *(uint4*)&Bs[r * 32 + swz(r, c & 3) * 8] = pack8(bv0[l], bv1[l]);
        }
        __syncthreads();

        bf16x8 a[2], b[4];
        #pragma unroll
        for (int i = 0; i < 2; ++i) {
            const int row = qm * 32 + i * 16 + al;
            a[i] = *(const bf16x8*)&As[row * 32 + swz(row, aq) * 8];
        }
        #pragma unroll
        for (int j = 0; j < 4; ++j) {
            const int row = qn * 64 + j * 16 + al;
            b[j] = *(const bf16x8*)&Bs[row * 32 + swz(row, aq) * 8];
        }
        #pragma unroll
        for (int i = 0; i < 2; ++i)
            #pragma unroll
            for (int j = 0; j < 4; ++j)
                acc[i][j] = __builtin_amdgcn_mfma_f32_16x16x32_bf16(
                    a[i], b[j], acc[i][j], 0, 0, 0);
    }

    #pragma unroll
    for (int i = 0; i < 2; ++i) {
        #pragma unroll
        for (int j = 0; j < 4; ++j) {
            const int row0 = bm + qm * 32 + i * 16 + aq * 4;
            const int col  = bn + qn * 64 + j * 16 + al;
            const float bv = bias[col];
            #pragma unroll
            for (int r = 0; r < 4; ++r)
                C[(long)(row0 + r) * N + col] = acc[i][j][r] + bv;
        }
    }
}

// ---------------------------------------------------------------------------
// Fused GRU step, 256-block edition. Grid = 64 j-tiles x 4 K-quarters so ALL
// 256 CUs share the 18 MB/step weight stream (R7's 64-block version was
// per-CU-BW-bound at 288 KB/CU). Block (J,kh): waves 0-2 = matrices
// (w_hh0 | w_ih1 | w_hh1), each 3 gates x 8 MFMA(16x16x32) over K-quarter;
// partials -> gpart[block] (disjoint slots, no atomics), __threadfence +
// counter post. kh==0 leader spins (~1us), sums 4 slots, does both cell
// updates. Deadlock-free by capacity: 256 blocks x 17 KB LDS all resident.
// ---------------------------------------------------------------------------
__global__ __launch_bounds__(256)
void fused_step2(const float* __restrict__ gx0_t,
                 const unsigned short* __restrict__ w0, const float* __restrict__ bb0,
                 const unsigned short* __restrict__ w1, const float* __restrict__ bb1,
                 const unsigned short* __restrict__ w2, const float* __restrict__ bb2,
                 const float* __restrict__ h1prev, float* __restrict__ h1out,
                 const float* __restrict__ h2prev, float* __restrict__ h2out,
                 float* __restrict__ gpart,   // [256 blk][9][16b][16j]
                 int* __restrict__ cnt,       // [64] zeroed, one per J
                 int k)
{
    __shared__ __attribute__((aligned(16))) unsigned short h1s[kB][264];
    __shared__ __attribute__((aligned(16))) unsigned short h2s[kB][264];

    const int tid   = threadIdx.x;     // 0..255
    const int lane  = tid & 63;
    const int wid   = tid >> 6;        // 0..3
    const int khq   = blockIdx.x & 3;  // K-quarter
    const int J     = blockIdx.x >> 2; // j-tile
    const int jbase = J * 16;
    const int kbase = khq * 256;

    const bool zeroA = (k == 0);
    const bool zeroB = (k <= 1);

    // ---- stage h1_{k-1}, h2_{k-2} K-slices -> bf16 LDS (1024 8-elt chunks)
    for (int c = tid; c < 1024; c += 256) {
        const int buf = c >> 9;              // 0: h1, 1: h2
        const int b   = (c >> 5) & 15;
        const int ko  = (c & 31) * 8;
        uint4 o = {0u, 0u, 0u, 0u};
        if (!(buf ? zeroB : zeroA)) {
            const float* src = (buf ? h2prev : h1prev) + (long)b * kH + kbase + ko;
            o = pack8(*(const float4*)(src), *(const float4*)(src + 4));
        }
        if (buf == 0) *(uint4*)&h1s[b][ko] = o;
        else          *(uint4*)&h2s[b][ko] = o;
    }
    __syncthreads();

    // ---- dots: wave m over its matrix, 3 gates x 8 k-steps ----
    if (wid < 3) {
        const int m = wid;
        const unsigned short* Wm = (m == 0) ? w0 : (m == 1) ? w1 : w2;
        const unsigned short* ab =
            ((m < 2) ? &h1s[0][0] : &h2s[0][0]) + (lane & 15) * 264 + (lane >> 4) * 8;
        const long wrow = (long)(jbase + (lane & 15)) * kH + kbase + (lane >> 4) * 8;

        floatx4 acc[3];
        #pragma unroll
        for (int g = 0; g < 3; ++g) acc[g] = (floatx4){0.f, 0.f, 0.f, 0.f};

        #pragma unroll
        for (int s = 0; s < 8; ++s) {
            const bf16x8 a = *(const bf16x8*)(ab + s * 32);
            #pragma unroll
            for (int g = 0; g < 3; ++g) {
                const bf16x8 bf = *(const bf16x8*)(Wm + (long)g * kH * kH + wrow + s * 32);
                acc[g] = __builtin_amdgcn_mfma_f32_16x16x32_bf16(a, bf, acc[g], 0, 0, 0);
            }
        }
        // partial store: D[b=(lane>>4)*4+r][j=lane&15]
        float* gp = gpart + (size_t)blockIdx.x * 9 * 256;
        const int aq = lane >> 4, al = lane & 15;
        #pragma unroll
        for (int g = 0; g < 3; ++g)
            #pragma unroll
            for (int r = 0; r < 4; ++r)
                gp[(m * 3 + g) * 256 + (aq * 4 + r) * 16 + al] = acc[g][r];
    }

    __threadfence();      // drain this thread's stores to device scope
    __syncthreads();      // all threads' fences complete
    if (tid == 0) atomicAdd(&cnt[J], 1);

    if (khq != 0) return;  // non-leaders done

    // ---- leader: wait for all 4 K-quarters, then cell updates ----
    if (tid == 0) {
        while (atomicAdd(&cnt[J], 0) < 4) __builtin_amdgcn_s_sleep(2);
    }
    __syncthreads();
    __threadfence();      // acquire: see partners' partial stores

    {
        const int b  = tid >> 4;
        const int jj = tid & 15;
        const int jg = jbase + jj;

        float gh[9];
        #pragma unroll
        for (int q = 0; q < 9; ++q) {
            float s = 0.f;
            #pragma unroll
            for (int kk = 0; kk < 4; ++kk)
                s += *(volatile const float*)(gpart
                        + ((size_t)(4 * J + kk) * 9 + q) * 256 + b * 16 + jj);
            gh[q] = s;
        }

        if (k < kT) {   // layer0 step t=k
            const float* gxrow = gx0_t + (long)b * (kT * 3 * kH);
            const float xr = gxrow[jg];
            const float xz = gxrow[kH + jg];
            const float xn = gxrow[2 * kH + jg];
            const float hr = gh[0] + bb0[jg];
            const float hz = gh[1] + bb0[kH + jg];
            const float hn = gh[2] + bb0[2 * kH + jg];
            const float hp = zeroA ? 0.f : h1prev[(long)b * kH + jg];
            const float r = 1.f / (1.f + __expf(-(xr + hr)));
            const float z = 1.f / (1.f + __expf(-(xz + hz)));
            const float n = tanhf(xn + r * hn);
            h1out[(long)b * kH + jg] = (1.f - z) * n + z * hp;
        }
        if (k > 0) {    // layer1 step t=k-1; gx1 = gh[3..5] + b_ih1
            const float xr = gh[3] + bb1[jg];
            const float xz = gh[4] + bb1[kH + jg];
            const float xn = gh[5] + bb1[2 * kH + jg];
            const float hr = gh[6] + bb2[jg];
            const float hz = gh[7] + bb2[kH + jg];
            const float hn = gh[8] + bb2[2 * kH + jg];
            const float hp = zeroB ? 0.f : h2prev[(long)b * kH + jg];
            const float r = 1.f / (1.f + __expf(-(xr + hr)));
            const float z = 1.f / (1.f + __expf(-(xz + hz)));
            const float n = tanhf(xn + r * hn);
            h2out[(long)b * kH + jg] = (1.f - z) * n + z * hp;
        }
    }
}

// ---------------------------------------------------------------------------
// kernel_launch
// ---------------------------------------------------------------------------
extern "C" void kernel_launch(void* const* d_in, const int* in_sizes, int n_in,
                              void* d_out, int out_size, void* d_ws, size_t ws_size,
                              hipStream_t stream)
{
    const float* x        = (const float*)d_in[0];   // [16,64,4096]
    const float* w_ih_l0  = (const float*)d_in[1];   // [3072,4096]
    const float* w_hh_l0  = (const float*)d_in[2];   // [3072,1024]
    const float* b_ih_l0  = (const float*)d_in[3];   // [3072]
    const float* b_hh_l0  = (const float*)d_in[4];   // [3072]
    const float* w_ih_l1  = (const float*)d_in[5];   // [3072,1024]
    const float* w_hh_l1  = (const float*)d_in[6];   // [3072,1024]
    const float* b_ih_l1  = (const float*)d_in[7];   // [3072]
    const float* b_hh_l1  = (const float*)d_in[8];   // [3072]
    const float* dec_w    = (const float*)d_in[9];   // [4096,1024]
    const float* dec_b    = (const float*)d_in[10];  // [4096]
    float* out = (float*)d_out;                      // [16,4096]

    // Workspace (~33 MB)
    float* ws    = (float*)d_ws;
    float* gx0   = ws;                                  // [1024,3072] rows b*T+t
    float* h1b0  = gx0 + (size_t)1024 * 3072;           // h1 ping-pong [16,1024]
    float* h1b1  = h1b0 + (size_t)kB * kH;
    float* h2b0  = h1b1 + (size_t)kB * kH;              // h2 ping-pong
    float* h2b1  = h2b0 + (size_t)kB * kH;
    float* gpart = h2b1 + (size_t)kB * kH;              // 256*9*256 = 2.36 MB
    int*   cnt   = (int*)(gpart + (size_t)256 * 9 * 256);          // [65][64]
    unsigned short* wbf0 = (unsigned short*)(cnt + 65 * 64);
    unsigned short* wbf1 = wbf0 + (size_t)3 * kH * kH;
    unsigned short* wbf2 = wbf1 + (size_t)3 * kH * kH;
    float* h1buf[2] = {h1b0, h1b1};
    float* h2buf[2] = {h2b0, h2b1};

    // zero the per-step counters (re-poisoned to 0xAA before every call)
    hipMemsetAsync(cnt, 0, 65 * 64 * sizeof(int), stream);

    const int wn4 = 3 * kH * kH / 4;
    pack_bf16<<<(wn4 + 255) / 256, 256, 0, stream>>>(w_hh_l0, wbf0, wn4);
    pack_bf16<<<(wn4 + 255) / 256, 256, 0, stream>>>(w_ih_l1, wbf1, wn4);
    pack_bf16<<<(wn4 + 255) / 256, 256, 0, stream>>>(w_hh_l1, wbf2, wn4);

    // Phase A (MFMA bf16): gx0 = x @ w_ih_l0^T + b_ih_l0  (M=1024,N=3072,K=4096)
    gemm_mfma_a<<<dim3(3072 / 128, 1024 / 64), 256, 0, stream>>>(
        x, w_ih_l0, b_ih_l0, gx0, 1024, 3072, 4096);

    // Fused pipelined recurrence: 65 launches, 256 blocks each.
    for (int k = 0; k <= kT; ++k) {
        const float* gx0_t  = gx0 + (size_t)(k < kT ? k : 0) * 3 * kH;
        const float* h1p = h1buf[(k + 1) & 1];   // h1_{k-1}
        float*       h1o = h1buf[k & 1];         // h1_k
        const float* h2p = h2buf[k & 1];         // h2_{k-2}
        float*       h2o = h2buf[(k + 1) & 1];   // h2_{k-1}
        fused_step2<<<256, 256, 0, stream>>>(
            gx0_t, wbf0, b_hh_l0, wbf1, b_ih_l1, wbf2, b_hh_l1,
            h1p, h1o, h2p, h2o, gpart, cnt + k * 64, k);
    }

    // Final h2 (t=63) is in h2buf[1].
    // Decoder (fp32): out = h2_last @ dec_w^T + dec_b  (M=16,N=4096,K=1024)
    gemm_nt_bias<<<dim3(4096 / GBN, 1), 256, 0, stream>>>(
        h2buf[1], dec_w, dec_b, out, kB, 4096, 1024);
}